// Round 16
// baseline (277.582 us; speedup 1.0000x reference)
//
#include <hip/hip_runtime.h>

#define E_      8
#define D_      1024
#define H_      2048
#define TOKENS  8192
#define RROWS   16384            // routed rows total (= TOKENS * TOP_K), exact
#define HPAD_ROWS (RROWS + 128)  // pad so GEMM2 A-staging over-read stays in bounds

using bf16x8 = __attribute__((ext_vector_type(8))) __bf16;
using f32x4  = __attribute__((ext_vector_type(4))) float;

__device__ __forceinline__ unsigned short f2bf(float f) {
  unsigned u = __builtin_bit_cast(unsigned, f);
  u += 0x7fffu + ((u >> 16) & 1u);   // RNE
  return (unsigned short)(u >> 16);
}
__device__ __forceinline__ float bf2f(unsigned short u) {
  unsigned v = (unsigned)u << 16;
  return __builtin_bit_cast(float, v);
}

// async global->LDS, 16B per lane; LDS dest is wave-uniform base + lane*16
#define GLDS16(g, l) __builtin_amdgcn_global_load_lds( \
    (const __attribute__((address_space(1))) unsigned int*)(g), \
    (__attribute__((address_space(3))) unsigned int*)(l), 16, 0, 0)

// ---------------- fused prologue (unchanged r15) ----------------

__global__ void prologue_kernel(const float* __restrict__ x, const float* __restrict__ gate,
                                unsigned short* __restrict__ xb,
                                int* __restrict__ sel, float* __restrict__ wsel,
                                const float* __restrict__ W1, unsigned short* __restrict__ w1t,
                                const float* __restrict__ W2, unsigned short* __restrict__ w2t) {
  __shared__ float tile[64][65];
  int b = blockIdx.x;
  const int NG = TOKENS / 4;
  if (b < NG) {
    int lane = threadIdx.x & 63, wid = threadIdx.x >> 6;
    int t = (b << 2) + wid;
    const float* xr = x + (size_t)t * D_;
    unsigned short* xbr = xb + (size_t)t * D_;
    float acc[8];
#pragma unroll
    for (int e = 0; e < 8; e++) acc[e] = 0.f;
#pragma unroll
    for (int i = 0; i < 4; i++) {
      int d0 = (i << 8) + (lane << 2);
      float4 xv = *reinterpret_cast<const float4*>(xr + d0);
      ushort4 o = make_ushort4(f2bf(xv.x), f2bf(xv.y), f2bf(xv.z), f2bf(xv.w));
      *reinterpret_cast<ushort4*>(xbr + d0) = o;
      float xa[4] = {xv.x, xv.y, xv.z, xv.w};
#pragma unroll
      for (int j = 0; j < 4; j++) {
        const float4* g4 = reinterpret_cast<const float4*>(gate + (size_t)(d0 + j) * 8);
        float4 ga = g4[0], gb = g4[1];
        acc[0] += xa[j] * ga.x; acc[1] += xa[j] * ga.y;
        acc[2] += xa[j] * ga.z; acc[3] += xa[j] * ga.w;
        acc[4] += xa[j] * gb.x; acc[5] += xa[j] * gb.y;
        acc[6] += xa[j] * gb.z; acc[7] += xa[j] * gb.w;
      }
    }
#pragma unroll
    for (int e = 0; e < 8; e++) {
#pragma unroll
      for (int off = 32; off; off >>= 1) acc[e] += __shfl_xor(acc[e], off);
    }
    if (lane == 0) {
      int i0 = 0; float v0 = acc[0];
#pragma unroll
      for (int e = 1; e < 8; e++) if (acc[e] > v0) { v0 = acc[e]; i0 = e; }
      int i1 = -1; float v1 = -3.4e38f;
#pragma unroll
      for (int e = 0; e < 8; e++) if (e != i0 && acc[e] > v1) { v1 = acc[e]; i1 = e; }
      float p1 = expf(v1 - v0);
      float inv = 1.f / (1.f + p1);
      sel[t * 2] = i0; sel[t * 2 + 1] = i1;
      wsel[t * 2] = inv; wsel[t * 2 + 1] = p1 * inv;
    }
    return;
  }
  b -= NG;
  const int nb1 = E_ * (D_ >> 6) * (H_ >> 6);
  const float* src; unsigned short* dst; int R, C;
  if (b < nb1) { src = W1; dst = w1t; R = D_; C = H_; }
  else         { src = W2; dst = w2t; R = H_; C = D_; b -= nb1; }
  int tilesC = C >> 6;
  int per = (R >> 6) * tilesC;
  int e = b / per, rem = b % per;
  int rb = rem / tilesC, cb = rem % tilesC;
  const float* s = src + (size_t)e * R * C;
  unsigned short* d = dst + (size_t)e * R * C;
  int r0 = rb << 6, c0 = cb << 6;
#pragma unroll
  for (int i = 0; i < 16; i++) {
    int idx = threadIdx.x + i * 256;
    int lr = idx >> 6, lc = idx & 63;
    tile[lr][lc] = s[(size_t)(r0 + lr) * C + (c0 + lc)];
  }
  __syncthreads();
#pragma unroll
  for (int i = 0; i < 16; i++) {
    int idx = threadIdx.x + i * 256;
    int lr = idx >> 6, lc = idx & 63;
    d[(size_t)(c0 + lr) * R + (r0 + lc)] = f2bf(tile[lc][lr]);
  }
}

// Deterministic atomic-free routing (unchanged r15)
__global__ __launch_bounds__(1024) void route_kernel(
    const int* __restrict__ sel, int* __restrict__ cnt, int* __restrict__ off,
    int* __restrict__ tok_id, int* __restrict__ pos) {
  const int tid = threadIdx.x;
  const int lane = tid & 63, wid = tid >> 6;
  __shared__ int wtot[16][8];
  __shared__ int woff[16][8];
  __shared__ int offs[8];
  int sv[16];
  const int s0 = tid << 4;
#pragma unroll
  for (int q = 0; q < 4; q++) {
    int4 v = reinterpret_cast<const int4*>(sel + s0)[q];
    sv[q * 4 + 0] = v.x; sv[q * 4 + 1] = v.y;
    sv[q * 4 + 2] = v.z; sv[q * 4 + 3] = v.w;
  }
  int h[8];
#pragma unroll
  for (int e = 0; e < 8; e++) h[e] = 0;
#pragma unroll
  for (int j = 0; j < 16; j++) {
    int ev = sv[j];
#pragma unroll
    for (int e = 0; e < 8; e++) h[e] += (ev == e) ? 1 : 0;
  }
  int excl[8];
#pragma unroll
  for (int e = 0; e < 8; e++) {
    int v = h[e];
#pragma unroll
    for (int d = 1; d < 64; d <<= 1) {
      int u = __shfl_up(v, d);
      if (lane >= d) v += u;
    }
    excl[e] = v - h[e];
    if (lane == 63) wtot[wid][e] = v;
  }
  __syncthreads();
  if (tid == 0) {
    int run[8];
#pragma unroll
    for (int e = 0; e < 8; e++) run[e] = 0;
    for (int w = 0; w < 16; w++)
#pragma unroll
      for (int e = 0; e < 8; e++) { woff[w][e] = run[e]; run[e] += wtot[w][e]; }
    int a = 0;
    for (int e = 0; e < 8; e++) { offs[e] = a; off[e] = a; cnt[e] = run[e]; a += run[e]; }
  }
  __syncthreads();
  int base[8];
#pragma unroll
  for (int e = 0; e < 8; e++) base[e] = offs[e] + woff[wid][e] + excl[e];
#pragma unroll
  for (int j = 0; j < 16; j++) {
    int ev = sv[j];
    int p = 0;
#pragma unroll
    for (int e = 0; e < 8; e++) if (ev == e) { p = base[e]; base[e] = p + 1; }
    pos[s0 + j] = p;
    tok_id[p] = (s0 + j) >> 1;
  }
}

// ---------------- grouped GEMMs: m97-style single-buffer (r15 winner) ----------------
// Serial stage -> sync -> compute -> sync loop; cross-block TLP does the
// pipelining (r15: gemm2 97us @ MfmaUtil 30%, VGPR 60, 0 conflicts, 0 spill).
// Swizzle: [row][128B] rows, chunk16 ^= (row&7) on per-lane GLOBAL source,
// LDS linear. r16 change: gemm1 widened to BM=128 x BN=256 (8 waves of the
// SAME 64x64 wave tile / 4x4 frags / same serial schedule) -> staged-byte
// intensity 64 -> 87 FLOP/B, A-panel restaging halved (cb 16 -> 8); LDS 48KB
// single-buffer -> 3 blocks/CU = 24 waves/CU. gemm2 unchanged (control).

__global__ __launch_bounds__(512, 2) void gemm1_kernel(
    const unsigned short* __restrict__ xb,    // [TOKENS][D_] bf16
    const unsigned short* __restrict__ w1t,   // [E][H][D] bf16 (k=d contiguous)
    const float* __restrict__ b1,             // [E][H]
    unsigned short* __restrict__ hbuf,        // [HPAD_ROWS][H_] bf16
    const int* __restrict__ tok_id,
    const int* __restrict__ cnt, const int* __restrict__ off) {
  const int nwg = E_ * 64 * 8;               // 4096
  const int raw = blockIdx.x;
  const int bid = (raw & 7) * (nwg >> 3) + (raw >> 3);   // expert e -> XCD e
  const int e  = bid >> 9;
  const int rb = (bid >> 3) & 63;
  const int cb = bid & 7;                    // n0 = cb*256 over H_
  const int rows = cnt[e];
  const int m0 = rb << 7;
  if (m0 >= rows) return;
  const int base = off[e];
  const int tid = threadIdx.x, lane = tid & 63, wid = tid >> 6;
  const int wr = wid >> 2, wc = wid & 3;     // 2 x 4 wave grid, 64x64 each

  __shared__ __align__(16) unsigned short Asm[128 * 64];   // 16 KB
  __shared__ __align__(16) unsigned short Bsm[256 * 64];   // 32 KB

  // staging: per instr, wave wid covers 8 rows (lane>>3) x 8 chunks (lane&7);
  // global chunk = (lane&7) ^ (row&7) = (lane&7) ^ (lane>>3 & 7).
  const int c8 = lane & 7, r8 = lane >> 3;
  const size_t swz = (size_t)((c8 ^ r8) << 4);
  const int n0 = cb << 8;
  size_t gA[2], gB[4];
#pragma unroll
  for (int i = 0; i < 2; i++) {
    int r = (i << 6) + (wid << 3) + r8;      // 0..127
    int ar = m0 + r; if (ar >= rows) ar = rows - 1;   // clamp (never stored)
    gA[i] = (size_t)tok_id[base + ar] * (D_ * 2) + swz;
  }
#pragma unroll
  for (int i = 0; i < 4; i++) {
    int r = (i << 6) + (wid << 3) + r8;      // 0..255
    gB[i] = (size_t)(n0 + r) * (D_ * 2) + swz;
  }
  const char* Ab = (const char*)xb;
  const char* Bb = (const char*)w1t + (size_t)e * H_ * D_ * 2;

  // fragment reads: A row = wr*64 + m*16 + (lane&15); B row = wc*64 + n*16 + (lane&15)
  const int aRow = ((wr << 6) + (lane & 15)) * 128;
  const int bRow = ((wc << 6) + (lane & 15)) * 128;
  const int cby0 = (((lane >> 4)) ^ (lane & 7)) << 4;
  const int cby1 = ((4 + (lane >> 4)) ^ (lane & 7)) << 4;

  f32x4 acc[4][4] = {};
  const int KH = D_ / 64;   // 16

  for (int kh = 0; kh < KH; ++kh) {
    const size_t ko = (size_t)kh << 7;
#pragma unroll
    for (int i = 0; i < 2; i++)
      GLDS16(Ab + gA[i] + ko, (char*)&Asm[0] + (i << 13) + (wid << 10));
#pragma unroll
    for (int i = 0; i < 4; i++)
      GLDS16(Bb + gB[i] + ko, (char*)&Bsm[0] + (i << 13) + (wid << 10));
    __syncthreads();                          // drains vmcnt: tile kh landed
    const char* Ap = (const char*)&Asm[0] + aRow;
    const char* Bp = (const char*)&Bsm[0] + bRow;
    bf16x8 a[4], b[4], a2[4], b2[4];
#pragma unroll
    for (int m = 0; m < 4; m++) a[m]  = *(const bf16x8*)(Ap + cby0 + m * 2048);
#pragma unroll
    for (int n = 0; n < 4; n++) b[n]  = *(const bf16x8*)(Bp + cby0 + n * 2048);
#pragma unroll
    for (int m = 0; m < 4; m++) a2[m] = *(const bf16x8*)(Ap + cby1 + m * 2048);
#pragma unroll
    for (int n = 0; n < 4; n++) b2[n] = *(const bf16x8*)(Bp + cby1 + n * 2048);
#pragma unroll
    for (int m = 0; m < 4; m++)
#pragma unroll
      for (int n = 0; n < 4; n++)
        acc[m][n] = __builtin_amdgcn_mfma_f32_16x16x32_bf16(a[m], b[n], acc[m][n], 0, 0, 0);
#pragma unroll
    for (int m = 0; m < 4; m++)
#pragma unroll
      for (int n = 0; n < 4; n++)
        acc[m][n] = __builtin_amdgcn_mfma_f32_16x16x32_bf16(a2[m], b2[n], acc[m][n], 0, 0, 0);
    __syncthreads();                          // all reads done before next stage
  }

  const int rcnt = rows - m0;
  const float* b1e = b1 + e * H_;
#pragma unroll
  for (int m = 0; m < 4; m++) {
#pragma unroll
    for (int q = 0; q < 4; q++) {
      int rl = (wr << 6) + (m << 4) + ((lane >> 4) << 2) + q;
      if (rl < rcnt) {
        unsigned short* hrow = hbuf + (size_t)(base + m0 + rl) * H_;
#pragma unroll
        for (int n = 0; n < 4; n++) {
          int ncol = n0 + (wc << 6) + (n << 4) + (lane & 15);
          float v = acc[m][n][q] + b1e[ncol];
          hrow[ncol] = f2bf(fmaxf(v, 0.f));
        }
      }
    }
  }
}

#define STAGE_A(kh) do { \
  const size_t ko = (size_t)(kh) << 7; \
  _Pragma("unroll") \
  for (int i = 0; i < 4; i++) \
    GLDS16(Ab + gA[i] + ko, &Asm[((wid << 2) + i) << 9]); \
} while (0)
#define STAGE_B(kh) do { \
  const size_t ko = (size_t)(kh) << 7; \
  _Pragma("unroll") \
  for (int i = 0; i < 4; i++) \
    GLDS16(Bb + gB[i] + ko, &Bsm[((wid << 2) + i) << 9]); \
} while (0)

__global__ __launch_bounds__(256, 2) void gemm2_kernel(
    const unsigned short* __restrict__ hbuf,  // [HPAD_ROWS][H_] bf16
    const unsigned short* __restrict__ w2t,   // [E][D][H] bf16 (k=h contiguous)
    unsigned short* __restrict__ eout,        // [RROWS][D_] bf16 (per-slot y)
    const int* __restrict__ cnt, const int* __restrict__ off) {
  const int nwg = E_ * 64 * 8;
  const int raw = blockIdx.x;
  const int bid = (raw & 7) * (nwg >> 3) + (raw >> 3);
  const int e  = bid >> 9;
  const int rb = (bid >> 3) & 63;
  const int cb = bid & 7;
  const int rows = cnt[e];
  const int m0 = rb << 7;
  if (m0 >= rows) return;
  const int base = off[e];
  const int tid = threadIdx.x, lane = tid & 63, wid = tid >> 6;
  const int wr = wid >> 1, wc = wid & 1;

  __shared__ __align__(16) unsigned short Asm[128 * 64];
  __shared__ __align__(16) unsigned short Bsm[128 * 64];

  const int c8 = lane & 7, r8 = lane >> 3;
  const size_t swz = (size_t)((c8 ^ r8) << 4);
  size_t gA[4], gB[4];
  const int n0 = cb << 7;
#pragma unroll
  for (int i = 0; i < 4; i++) {
    int r = ((wid << 2) + i) << 3;
    gA[i] = (size_t)(base + m0 + r + r8) * (H_ * 2) + swz;  // pad-safe overread
    gB[i] = (size_t)(n0 + r + r8) * (H_ * 2) + swz;
  }
  const char* Ab = (const char*)hbuf;
  const char* Bb = (const char*)w2t + (size_t)e * D_ * H_ * 2;

  const int aRow = ((wr << 6) + (lane & 15)) * 128;
  const int bRow = ((wc << 6) + (lane & 15)) * 128;
  const int cby0 = (((lane >> 4)) ^ (lane & 7)) << 4;
  const int cby1 = ((4 + (lane >> 4)) ^ (lane & 7)) << 4;

  f32x4 acc[4][4] = {};
  const int KH = H_ / 64;   // 32

  for (int kh = 0; kh < KH; ++kh) {
    STAGE_A(kh); STAGE_B(kh);
    __syncthreads();
    const char* Ap = (const char*)&Asm[0] + aRow;
    const char* Bp = (const char*)&Bsm[0] + bRow;
    bf16x8 a[4], b[4], a2[4], b2[4];
#pragma unroll
    for (int m = 0; m < 4; m++) a[m]  = *(const bf16x8*)(Ap + cby0 + m * 2048);
#pragma unroll
    for (int n = 0; n < 4; n++) b[n]  = *(const bf16x8*)(Bp + cby0 + n * 2048);
#pragma unroll
    for (int m = 0; m < 4; m++) a2[m] = *(const bf16x8*)(Ap + cby1 + m * 2048);
#pragma unroll
    for (int n = 0; n < 4; n++) b2[n] = *(const bf16x8*)(Bp + cby1 + n * 2048);
#pragma unroll
    for (int m = 0; m < 4; m++)
#pragma unroll
      for (int n = 0; n < 4; n++)
        acc[m][n] = __builtin_amdgcn_mfma_f32_16x16x32_bf16(a[m], b[n], acc[m][n], 0, 0, 0);
#pragma unroll
    for (int m = 0; m < 4; m++)
#pragma unroll
      for (int n = 0; n < 4; n++)
        acc[m][n] = __builtin_amdgcn_mfma_f32_16x16x32_bf16(a2[m], b2[n], acc[m][n], 0, 0, 0);
    __syncthreads();
  }

  const int rcnt = rows - m0;
#pragma unroll
  for (int m = 0; m < 4; m++) {
#pragma unroll
    for (int q = 0; q < 4; q++) {
      int rl = (wr << 6) + (m << 4) + ((lane >> 4) << 2) + q;
      if (rl < rcnt) {
        unsigned short* erow = eout + (size_t)(base + m0 + rl) * D_;
#pragma unroll
        for (int n = 0; n < 4; n++) {
          int ncol = n0 + (wc << 6) + (n << 4) + (lane & 15);
          erow[ncol] = f2bf(acc[m][n][q]);
        }
      }
    }
  }
}

// out[t] = w0*(eout[p0] + b2[e0]) + w1*(eout[p1] + b2[e1]); 4 tokens/block
__global__ void combine_kernel(const unsigned short* __restrict__ eout,
                               const float* __restrict__ b2,
                               const int* __restrict__ sel, const float* __restrict__ wsel,
                               const int* __restrict__ pos,
                               float* __restrict__ out) {
  int t = (blockIdx.x << 2) + (threadIdx.x >> 6);
  int lane = threadIdx.x & 63;
  int e0 = sel[t * 2], e1 = sel[t * 2 + 1];
  float w0 = wsel[t * 2], w1 = wsel[t * 2 + 1];
  int p0 = pos[t * 2], p1 = pos[t * 2 + 1];
  const unsigned short* y0r = eout + (size_t)p0 * D_;
  const unsigned short* y1r = eout + (size_t)p1 * D_;
  const float* c0r = b2 + (size_t)e0 * D_;
  const float* c1r = b2 + (size_t)e1 * D_;
  float* orow = out + (size_t)t * D_;
#pragma unroll
  for (int j = 0; j < 4; j++) {
    int d = (j << 8) + (lane << 2);
    ushort4 y0 = *reinterpret_cast<const ushort4*>(y0r + d);
    ushort4 y1 = *reinterpret_cast<const ushort4*>(y1r + d);
    float4 c0 = *reinterpret_cast<const float4*>(c0r + d);
    float4 c1 = *reinterpret_cast<const float4*>(c1r + d);
    float4 o;
    o.x = w0 * (bf2f(y0.x) + c0.x) + w1 * (bf2f(y1.x) + c1.x);
    o.y = w0 * (bf2f(y0.y) + c0.y) + w1 * (bf2f(y1.y) + c1.y);
    o.z = w0 * (bf2f(y0.z) + c0.z) + w1 * (bf2f(y1.z) + c1.z);
    o.w = w0 * (bf2f(y0.w) + c0.w) + w1 * (bf2f(y1.w) + c1.w);
    *reinterpret_cast<float4*>(orow + d) = o;
  }
}

// ---------------- launcher ----------------

extern "C" void kernel_launch(void* const* d_in, const int* in_sizes, int n_in,
                              void* d_out, int out_size, void* d_ws, size_t ws_size,
                              hipStream_t stream) {
  (void)in_sizes; (void)n_in; (void)ws_size; (void)out_size;
  const float* x    = (const float*)d_in[0];
  const float* gate = (const float*)d_in[1];
  const float* W1   = (const float*)d_in[2];
  const float* b1   = (const float*)d_in[3];
  const float* W2   = (const float*)d_in[4];
  const float* b2   = (const float*)d_in[5];
  float* out = (float*)d_out;

  char* p = (char*)d_ws;
  unsigned short* xb   = (unsigned short*)p; p += (size_t)TOKENS * D_ * 2;
  unsigned short* w1t  = (unsigned short*)p; p += (size_t)E_ * H_ * D_ * 2;
  unsigned short* w2t  = (unsigned short*)p; p += (size_t)E_ * D_ * H_ * 2;
  unsigned short* hbuf = (unsigned short*)p; p += (size_t)HPAD_ROWS * H_ * 2;
  int*   tok  = (int*)p;   p += (size_t)RROWS * 4;
  int*   pos  = (int*)p;   p += (size_t)TOKENS * 2 * 4;
  int*   sel  = (int*)p;   p += (size_t)TOKENS * 2 * 4;
  float* wsel = (float*)p; p += (size_t)TOKENS * 2 * 4;
  int* cnt    = (int*)p;   p += 32 * 4;
  int* off    = (int*)p;   p += 32 * 4;
  // eout aliases w1t (dead after gemm1; same size; rewritten each replay)
  unsigned short* eout = w1t;

  const int nb1 = E_ * (D_ / 64) * (H_ / 64);
  const int nb2 = E_ * (H_ / 64) * (D_ / 64);
  prologue_kernel<<<TOKENS / 4 + nb1 + nb2, 256, 0, stream>>>(
      x, gate, xb, sel, wsel, W1, w1t, W2, w2t);
  route_kernel<<<1, 1024, 0, stream>>>(sel, cnt, off, tok, pos);
  gemm1_kernel<<<E_ * 64 * 8, 512, 0, stream>>>(xb, w1t, b1, hbuf, tok, cnt, off);
  gemm2_kernel<<<E_ * 64 * 8, 256, 0, stream>>>(hbuf, w2t, eout, cnt, off);
  combine_kernel<<<TOKENS / 4, 256, 0, stream>>>(eout, b2, sel, wsel, pos, out);
}

// Round 17
// 266.481 us; speedup vs baseline: 1.0417x; 1.0417x over previous
//
#include <hip/hip_runtime.h>

#define E_      8
#define D_      1024
#define H_      2048
#define TOKENS  8192
#define RROWS   16384            // routed rows total (= TOKENS * TOP_K), exact
#define HPAD_ROWS (RROWS + 128)  // pad so GEMM2 A-staging over-read stays in bounds

using bf16x8 = __attribute__((ext_vector_type(8))) __bf16;
using f32x4  = __attribute__((ext_vector_type(4))) float;

__device__ __forceinline__ unsigned short f2bf(float f) {
  unsigned u = __builtin_bit_cast(unsigned, f);
  u += 0x7fffu + ((u >> 16) & 1u);   // RNE
  return (unsigned short)(u >> 16);
}
__device__ __forceinline__ float bf2f(unsigned short u) {
  unsigned v = (unsigned)u << 16;
  return __builtin_bit_cast(float, v);
}

// async global->LDS, 16B per lane; LDS dest is wave-uniform base + lane*16
#define GLDS16(g, l) __builtin_amdgcn_global_load_lds( \
    (const __attribute__((address_space(1))) unsigned int*)(g), \
    (__attribute__((address_space(3))) unsigned int*)(l), 16, 0, 0)

// ---------------- prologue: gating + W1 transpose only ----------------
// (W2 transpose moved into gemm1's grid tail — it has no dependents until
// gemm2, and gemm1 runs at only ~10% HBM so the transpose hides under it.)

__global__ void gate_w1_kernel(const float* __restrict__ x, const float* __restrict__ gate,
                               unsigned short* __restrict__ xb,
                               int* __restrict__ sel, float* __restrict__ wsel,
                               const float* __restrict__ W1, unsigned short* __restrict__ w1t) {
  __shared__ float tile[64][65];
  int b = blockIdx.x;
  const int NG = TOKENS / 4;
  if (b < NG) {
    int lane = threadIdx.x & 63, wid = threadIdx.x >> 6;
    int t = (b << 2) + wid;
    const float* xr = x + (size_t)t * D_;
    unsigned short* xbr = xb + (size_t)t * D_;
    float acc[8];
#pragma unroll
    for (int e = 0; e < 8; e++) acc[e] = 0.f;
#pragma unroll
    for (int i = 0; i < 4; i++) {
      int d0 = (i << 8) + (lane << 2);
      float4 xv = *reinterpret_cast<const float4*>(xr + d0);
      ushort4 o = make_ushort4(f2bf(xv.x), f2bf(xv.y), f2bf(xv.z), f2bf(xv.w));
      *reinterpret_cast<ushort4*>(xbr + d0) = o;
      float xa[4] = {xv.x, xv.y, xv.z, xv.w};
#pragma unroll
      for (int j = 0; j < 4; j++) {
        const float4* g4 = reinterpret_cast<const float4*>(gate + (size_t)(d0 + j) * 8);
        float4 ga = g4[0], gb = g4[1];
        acc[0] += xa[j] * ga.x; acc[1] += xa[j] * ga.y;
        acc[2] += xa[j] * ga.z; acc[3] += xa[j] * ga.w;
        acc[4] += xa[j] * gb.x; acc[5] += xa[j] * gb.y;
        acc[6] += xa[j] * gb.z; acc[7] += xa[j] * gb.w;
      }
    }
#pragma unroll
    for (int e = 0; e < 8; e++) {
#pragma unroll
      for (int off = 32; off; off >>= 1) acc[e] += __shfl_xor(acc[e], off);
    }
    if (lane == 0) {
      int i0 = 0; float v0 = acc[0];
#pragma unroll
      for (int e = 1; e < 8; e++) if (acc[e] > v0) { v0 = acc[e]; i0 = e; }
      int i1 = -1; float v1 = -3.4e38f;
#pragma unroll
      for (int e = 0; e < 8; e++) if (e != i0 && acc[e] > v1) { v1 = acc[e]; i1 = e; }
      float p1 = expf(v1 - v0);
      float inv = 1.f / (1.f + p1);
      sel[t * 2] = i0; sel[t * 2 + 1] = i1;
      wsel[t * 2] = inv; wsel[t * 2 + 1] = p1 * inv;
    }
    return;
  }
  // W1 transpose: [E][D][H] fp32 -> [E][H][D] bf16
  b -= NG;
  const int tilesC = H_ >> 6;
  const int per = (D_ >> 6) * tilesC;
  int e = b / per, rem = b % per;
  int rb = rem / tilesC, cb = rem % tilesC;
  const float* s = W1 + (size_t)e * D_ * H_;
  unsigned short* d = w1t + (size_t)e * D_ * H_;
  int r0 = rb << 6, c0 = cb << 6;
#pragma unroll
  for (int i = 0; i < 16; i++) {
    int idx = threadIdx.x + i * 256;
    int lr = idx >> 6, lc = idx & 63;
    tile[lr][lc] = s[(size_t)(r0 + lr) * H_ + (c0 + lc)];
  }
  __syncthreads();
#pragma unroll
  for (int i = 0; i < 16; i++) {
    int idx = threadIdx.x + i * 256;
    int lr = idx >> 6, lc = idx & 63;
    d[(size_t)(c0 + lr) * D_ + (r0 + lc)] = f2bf(tile[lc][lr]);
  }
}

// Deterministic atomic-free routing (unchanged r15)
__global__ __launch_bounds__(1024) void route_kernel(
    const int* __restrict__ sel, int* __restrict__ cnt, int* __restrict__ off,
    int* __restrict__ tok_id, int* __restrict__ pos) {
  const int tid = threadIdx.x;
  const int lane = tid & 63, wid = tid >> 6;
  __shared__ int wtot[16][8];
  __shared__ int woff[16][8];
  __shared__ int offs[8];
  int sv[16];
  const int s0 = tid << 4;
#pragma unroll
  for (int q = 0; q < 4; q++) {
    int4 v = reinterpret_cast<const int4*>(sel + s0)[q];
    sv[q * 4 + 0] = v.x; sv[q * 4 + 1] = v.y;
    sv[q * 4 + 2] = v.z; sv[q * 4 + 3] = v.w;
  }
  int h[8];
#pragma unroll
  for (int e = 0; e < 8; e++) h[e] = 0;
#pragma unroll
  for (int j = 0; j < 16; j++) {
    int ev = sv[j];
#pragma unroll
    for (int e = 0; e < 8; e++) h[e] += (ev == e) ? 1 : 0;
  }
  int excl[8];
#pragma unroll
  for (int e = 0; e < 8; e++) {
    int v = h[e];
#pragma unroll
    for (int d = 1; d < 64; d <<= 1) {
      int u = __shfl_up(v, d);
      if (lane >= d) v += u;
    }
    excl[e] = v - h[e];
    if (lane == 63) wtot[wid][e] = v;
  }
  __syncthreads();
  if (tid == 0) {
    int run[8];
#pragma unroll
    for (int e = 0; e < 8; e++) run[e] = 0;
    for (int w = 0; w < 16; w++)
#pragma unroll
      for (int e = 0; e < 8; e++) { woff[w][e] = run[e]; run[e] += wtot[w][e]; }
    int a = 0;
    for (int e = 0; e < 8; e++) { offs[e] = a; off[e] = a; cnt[e] = run[e]; a += run[e]; }
  }
  __syncthreads();
  int base[8];
#pragma unroll
  for (int e = 0; e < 8; e++) base[e] = offs[e] + woff[wid][e] + excl[e];
#pragma unroll
  for (int j = 0; j < 16; j++) {
    int ev = sv[j];
    int p = 0;
#pragma unroll
    for (int e = 0; e < 8; e++) if (ev == e) { p = base[e]; base[e] = p + 1; }
    pos[s0 + j] = p;
    tok_id[p] = (s0 + j) >> 1;
  }
}

// ---------------- grouped GEMMs: m97-style single-buffer (r15 winner) ----------------
// Serial stage -> sync -> compute -> sync loop; cross-block TLP does the
// pipelining (r15: ~97us/GEMM @ MfmaUtil 30%, 0 conflicts, 0 spill).
// Swizzle: [row][128B] rows, chunk16 ^= (row&7) on per-lane GLOBAL source,
// LDS linear. gemm1 grid carries nb2 tail blocks doing the W2 transpose
// (independent work, hidden under gemm1's compute-bound phase).

#define STAGE_A(kh) do { \
  const size_t ko = (size_t)(kh) << 7; \
  _Pragma("unroll") \
  for (int i = 0; i < 4; i++) \
    GLDS16(Ab + gA[i] + ko, &Asm[((wid << 2) + i) << 9]); \
} while (0)
#define STAGE_B(kh) do { \
  const size_t ko = (size_t)(kh) << 7; \
  _Pragma("unroll") \
  for (int i = 0; i < 4; i++) \
    GLDS16(Bb + gB[i] + ko, &Bsm[((wid << 2) + i) << 9]); \
} while (0)

__global__ __launch_bounds__(256, 2) void gemm1_kernel(
    const unsigned short* __restrict__ xb,    // [TOKENS][D_] bf16
    const unsigned short* __restrict__ w1t,   // [E][H][D] bf16 (k=d contiguous)
    const float* __restrict__ b1,             // [E][H]
    unsigned short* __restrict__ hbuf,        // [HPAD_ROWS][H_] bf16
    const int* __restrict__ tok_id,
    const int* __restrict__ cnt, const int* __restrict__ off,
    const float* __restrict__ W2, unsigned short* __restrict__ w2t) {
  __shared__ __align__(16) char smem[32768];
  unsigned short* Asm = (unsigned short*)smem;          // 16 KB
  unsigned short* Bsm = (unsigned short*)(smem + 16384);

  const int nwg = E_ * 64 * 16;
  const int raw = blockIdx.x;
  if (raw >= nwg) {
    // ---- W2 transpose tail block: [E][H][D] fp32 -> [E][D][H] bf16 ----
    float (*tile)[65] = (float(*)[65])smem;             // 16.6 KB < 32 KB
    int b = raw - nwg;
    const int tilesC = D_ >> 6;
    const int per = (H_ >> 6) * tilesC;
    int e = b / per, rem = b % per;
    int rb = rem / tilesC, cb = rem % tilesC;
    const float* s = W2 + (size_t)e * H_ * D_;
    unsigned short* d = w2t + (size_t)e * H_ * D_;
    int r0 = rb << 6, c0 = cb << 6;
#pragma unroll
    for (int i = 0; i < 16; i++) {
      int idx = threadIdx.x + i * 256;
      int lr = idx >> 6, lc = idx & 63;
      tile[lr][lc] = s[(size_t)(r0 + lr) * D_ + (c0 + lc)];
    }
    __syncthreads();
#pragma unroll
    for (int i = 0; i < 16; i++) {
      int idx = threadIdx.x + i * 256;
      int lr = idx >> 6, lc = idx & 63;
      d[(size_t)(c0 + lr) * H_ + (r0 + lc)] = f2bf(tile[lc][lr]);
    }
    return;
  }

  const int bid = (raw & 7) * (nwg >> 3) + (raw >> 3);
  const int e  = bid >> 10;
  const int rb = (bid >> 4) & 63;
  const int cb = bid & 15;
  const int rows = cnt[e];
  const int m0 = rb << 7;
  if (m0 >= rows) return;
  const int base = off[e];
  const int tid = threadIdx.x, lane = tid & 63, wid = tid >> 6;
  const int wr = wid >> 1, wc = wid & 1;

  // staging: issue i covers rows ((wid*4+i)*8 .. +7); lane: r8 = lane>>3 row,
  // c8 = lane&7 chunk; global chunk = c8 ^ (row&7) = c8 ^ r8.
  const int c8 = lane & 7, r8 = lane >> 3;
  const size_t swz = (size_t)((c8 ^ r8) << 4);
  size_t gA[4], gB[4];
  const int n0 = cb << 7;
#pragma unroll
  for (int i = 0; i < 4; i++) {
    int r = ((wid << 2) + i) << 3;
    int ar = m0 + r + r8; if (ar >= rows) ar = rows - 1;   // clamp (never stored)
    gA[i] = (size_t)tok_id[base + ar] * (D_ * 2) + swz;
    gB[i] = (size_t)(n0 + r + r8) * (D_ * 2) + swz;
  }
  const char* Ab = (const char*)xb;
  const char* Bb = (const char*)w1t + (size_t)e * H_ * D_ * 2;

  // fragment reads: row = w*64 + (lane&15), chunk = ((kk*4 + lane>>4) ^ (row&7))
  const int aRow = ((wr << 6) + (lane & 15)) * 128;
  const int bRow = ((wc << 6) + (lane & 15)) * 128;
  const int cby0 = (((lane >> 4)) ^ (lane & 7)) << 4;
  const int cby1 = ((4 + (lane >> 4)) ^ (lane & 7)) << 4;

  f32x4 acc[4][4] = {};
  const int KH = D_ / 64;   // 16

  for (int kh = 0; kh < KH; ++kh) {
    STAGE_A(kh); STAGE_B(kh);
    __syncthreads();                          // drains vmcnt: tile kh landed
    const char* Ap = (const char*)Asm + aRow;
    const char* Bp = (const char*)Bsm + bRow;
    bf16x8 a[4], b[4], a2[4], b2[4];
#pragma unroll
    for (int m = 0; m < 4; m++) a[m]  = *(const bf16x8*)(Ap + cby0 + m * 2048);
#pragma unroll
    for (int n = 0; n < 4; n++) b[n]  = *(const bf16x8*)(Bp + cby0 + n * 2048);
#pragma unroll
    for (int m = 0; m < 4; m++) a2[m] = *(const bf16x8*)(Ap + cby1 + m * 2048);
#pragma unroll
    for (int n = 0; n < 4; n++) b2[n] = *(const bf16x8*)(Bp + cby1 + n * 2048);
#pragma unroll
    for (int m = 0; m < 4; m++)
#pragma unroll
      for (int n = 0; n < 4; n++)
        acc[m][n] = __builtin_amdgcn_mfma_f32_16x16x32_bf16(a[m], b[n], acc[m][n], 0, 0, 0);
#pragma unroll
    for (int m = 0; m < 4; m++)
#pragma unroll
      for (int n = 0; n < 4; n++)
        acc[m][n] = __builtin_amdgcn_mfma_f32_16x16x32_bf16(a2[m], b2[n], acc[m][n], 0, 0, 0);
    __syncthreads();                          // all reads done before next stage
  }

  const int rcnt = rows - m0;
  const float* b1e = b1 + e * H_;
#pragma unroll
  for (int m = 0; m < 4; m++) {
#pragma unroll
    for (int q = 0; q < 4; q++) {
      int rl = (wr << 6) + (m << 4) + ((lane >> 4) << 2) + q;
      if (rl < rcnt) {
        unsigned short* hrow = hbuf + (size_t)(base + m0 + rl) * H_;
#pragma unroll
        for (int n = 0; n < 4; n++) {
          int ncol = n0 + (wc << 6) + (n << 4) + (lane & 15);
          float v = acc[m][n][q] + b1e[ncol];
          hrow[ncol] = f2bf(fmaxf(v, 0.f));
        }
      }
    }
  }
}

__global__ __launch_bounds__(256, 2) void gemm2_kernel(
    const unsigned short* __restrict__ hbuf,  // [HPAD_ROWS][H_] bf16
    const unsigned short* __restrict__ w2t,   // [E][D][H] bf16 (k=h contiguous)
    unsigned short* __restrict__ eout,        // [RROWS][D_] bf16 (per-slot y)
    const int* __restrict__ cnt, const int* __restrict__ off) {
  const int nwg = E_ * 64 * 8;
  const int raw = blockIdx.x;
  const int bid = (raw & 7) * (nwg >> 3) + (raw >> 3);
  const int e  = bid >> 9;
  const int rb = (bid >> 3) & 63;
  const int cb = bid & 7;
  const int rows = cnt[e];
  const int m0 = rb << 7;
  if (m0 >= rows) return;
  const int base = off[e];
  const int tid = threadIdx.x, lane = tid & 63, wid = tid >> 6;
  const int wr = wid >> 1, wc = wid & 1;

  __shared__ __align__(16) unsigned short Asm[128 * 64];
  __shared__ __align__(16) unsigned short Bsm[128 * 64];

  const int c8 = lane & 7, r8 = lane >> 3;
  const size_t swz = (size_t)((c8 ^ r8) << 4);
  size_t gA[4], gB[4];
  const int n0 = cb << 7;
#pragma unroll
  for (int i = 0; i < 4; i++) {
    int r = ((wid << 2) + i) << 3;
    gA[i] = (size_t)(base + m0 + r + r8) * (H_ * 2) + swz;  // pad-safe overread
    gB[i] = (size_t)(n0 + r + r8) * (H_ * 2) + swz;
  }
  const char* Ab = (const char*)hbuf;
  const char* Bb = (const char*)w2t + (size_t)e * D_ * H_ * 2;

  const int aRow = ((wr << 6) + (lane & 15)) * 128;
  const int bRow = ((wc << 6) + (lane & 15)) * 128;
  const int cby0 = (((lane >> 4)) ^ (lane & 7)) << 4;
  const int cby1 = ((4 + (lane >> 4)) ^ (lane & 7)) << 4;

  f32x4 acc[4][4] = {};
  const int KH = H_ / 64;   // 32

  for (int kh = 0; kh < KH; ++kh) {
    STAGE_A(kh); STAGE_B(kh);
    __syncthreads();
    const char* Ap = (const char*)&Asm[0] + aRow;
    const char* Bp = (const char*)&Bsm[0] + bRow;
    bf16x8 a[4], b[4], a2[4], b2[4];
#pragma unroll
    for (int m = 0; m < 4; m++) a[m]  = *(const bf16x8*)(Ap + cby0 + m * 2048);
#pragma unroll
    for (int n = 0; n < 4; n++) b[n]  = *(const bf16x8*)(Bp + cby0 + n * 2048);
#pragma unroll
    for (int m = 0; m < 4; m++) a2[m] = *(const bf16x8*)(Ap + cby1 + m * 2048);
#pragma unroll
    for (int n = 0; n < 4; n++) b2[n] = *(const bf16x8*)(Bp + cby1 + n * 2048);
#pragma unroll
    for (int m = 0; m < 4; m++)
#pragma unroll
      for (int n = 0; n < 4; n++)
        acc[m][n] = __builtin_amdgcn_mfma_f32_16x16x32_bf16(a[m], b[n], acc[m][n], 0, 0, 0);
#pragma unroll
    for (int m = 0; m < 4; m++)
#pragma unroll
      for (int n = 0; n < 4; n++)
        acc[m][n] = __builtin_amdgcn_mfma_f32_16x16x32_bf16(a2[m], b2[n], acc[m][n], 0, 0, 0);
    __syncthreads();
  }

  const int rcnt = rows - m0;
#pragma unroll
  for (int m = 0; m < 4; m++) {
#pragma unroll
    for (int q = 0; q < 4; q++) {
      int rl = (wr << 6) + (m << 4) + ((lane >> 4) << 2) + q;
      if (rl < rcnt) {
        unsigned short* erow = eout + (size_t)(base + m0 + rl) * D_;
#pragma unroll
        for (int n = 0; n < 4; n++) {
          int ncol = n0 + (wc << 6) + (n << 4) + (lane & 15);
          erow[ncol] = f2bf(acc[m][n][q]);
        }
      }
    }
  }
}

// out[t] = w0*(eout[p0] + b2[e0]) + w1*(eout[p1] + b2[e1]); 4 tokens/block
__global__ void combine_kernel(const unsigned short* __restrict__ eout,
                               const float* __restrict__ b2,
                               const int* __restrict__ sel, const float* __restrict__ wsel,
                               const int* __restrict__ pos,
                               float* __restrict__ out) {
  int t = (blockIdx.x << 2) + (threadIdx.x >> 6);
  int lane = threadIdx.x & 63;
  int e0 = sel[t * 2], e1 = sel[t * 2 + 1];
  float w0 = wsel[t * 2], w1 = wsel[t * 2 + 1];
  int p0 = pos[t * 2], p1 = pos[t * 2 + 1];
  const unsigned short* y0r = eout + (size_t)p0 * D_;
  const unsigned short* y1r = eout + (size_t)p1 * D_;
  const float* c0r = b2 + (size_t)e0 * D_;
  const float* c1r = b2 + (size_t)e1 * D_;
  float* orow = out + (size_t)t * D_;
#pragma unroll
  for (int j = 0; j < 4; j++) {
    int d = (j << 8) + (lane << 2);
    ushort4 y0 = *reinterpret_cast<const ushort4*>(y0r + d);
    ushort4 y1 = *reinterpret_cast<const ushort4*>(y1r + d);
    float4 c0 = *reinterpret_cast<const float4*>(c0r + d);
    float4 c1 = *reinterpret_cast<const float4*>(c1r + d);
    float4 o;
    o.x = w0 * (bf2f(y0.x) + c0.x) + w1 * (bf2f(y1.x) + c1.x);
    o.y = w0 * (bf2f(y0.y) + c0.y) + w1 * (bf2f(y1.y) + c1.y);
    o.z = w0 * (bf2f(y0.z) + c0.z) + w1 * (bf2f(y1.z) + c1.z);
    o.w = w0 * (bf2f(y0.w) + c0.w) + w1 * (bf2f(y1.w) + c1.w);
    *reinterpret_cast<float4*>(orow + d) = o;
  }
}

// ---------------- launcher ----------------

extern "C" void kernel_launch(void* const* d_in, const int* in_sizes, int n_in,
                              void* d_out, int out_size, void* d_ws, size_t ws_size,
                              hipStream_t stream) {
  (void)in_sizes; (void)n_in; (void)ws_size; (void)out_size;
  const float* x    = (const float*)d_in[0];
  const float* gate = (const float*)d_in[1];
  const float* W1   = (const float*)d_in[2];
  const float* b1   = (const float*)d_in[3];
  const float* W2   = (const float*)d_in[4];
  const float* b2   = (const float*)d_in[5];
  float* out = (float*)d_out;

  char* p = (char*)d_ws;
  unsigned short* xb   = (unsigned short*)p; p += (size_t)TOKENS * D_ * 2;
  unsigned short* w1t  = (unsigned short*)p; p += (size_t)E_ * H_ * D_ * 2;
  unsigned short* w2t  = (unsigned short*)p; p += (size_t)E_ * D_ * H_ * 2;
  unsigned short* hbuf = (unsigned short*)p; p += (size_t)HPAD_ROWS * H_ * 2;
  int*   tok  = (int*)p;   p += (size_t)RROWS * 4;
  int*   pos  = (int*)p;   p += (size_t)TOKENS * 2 * 4;
  int*   sel  = (int*)p;   p += (size_t)TOKENS * 2 * 4;
  float* wsel = (float*)p; p += (size_t)TOKENS * 2 * 4;
  int* cnt    = (int*)p;   p += 32 * 4;
  int* off    = (int*)p;   p += 32 * 4;
  // eout aliases w1t (dead after gemm1; same size; rewritten each replay)
  unsigned short* eout = w1t;

  const int nb1 = E_ * (D_ / 64) * (H_ / 64);
  const int nb2 = E_ * (H_ / 64) * (D_ / 64);
  gate_w1_kernel<<<TOKENS / 4 + nb1, 256, 0, stream>>>(x, gate, xb, sel, wsel, W1, w1t);
  route_kernel<<<1, 1024, 0, stream>>>(sel, cnt, off, tok, pos);
  gemm1_kernel<<<E_ * 64 * 16 + nb2, 256, 0, stream>>>(xb, w1t, b1, hbuf, tok, cnt, off, W2, w2t);
  gemm2_kernel<<<E_ * 64 * 8, 256, 0, stream>>>(hbuf, w2t, eout, cnt, off);
  combine_kernel<<<TOKENS / 4, 256, 0, stream>>>(eout, b2, sel, wsel, pos, out);
}